// Round 1
// 256.921 us; speedup vs baseline: 1.0432x; 1.0432x over previous
//
#include <hip/hip_runtime.h>
#include <hip/hip_bf16.h>

// LoKr: out = x @ kron(w1, a@b).T * S, factored into 3 small GEMMs.
// x view: [65536 A-rows (pos*8+ij) x 512 il], b: [64 r x 512 il],
// a: [512 ok x 64 r], out row (pos*8+oi) x 512 ok  (contiguous since
// pos*4096 + oi*512 = (pos*8+oi)*512).
//
// R3->R4: latency/occupancy fix. Counters showed all pipes idle (Mfma 3%,
// VALU 6%, HBM 31%, Occ 16%): LDS 55.8KB + grid 512 capped us at 2
// blocks/CU = 2 waves/SIMD -> prefetch-depth-1 slab pipeline fully exposed
// HBM latency. Now: 64-row tiles (grid 1024), vs aliased onto xs[0]
// (LDS 18.7KB), launch_bounds(256,4) -> 4 resident blocks/CU = 16
// waves/CU with de-correlated barriers. Stage-3 MFMA operands swapped
// (C transposed) so each lane holds 4 consecutive ok -> float4 stores
// (4x fewer store instrs). b/a fragments prefetched one step ahead.

typedef __attribute__((ext_vector_type(4))) float f32x4;
typedef __attribute__((ext_vector_type(8))) short s16x8;
typedef __attribute__((ext_vector_type(4))) short s16x4;

__device__ inline unsigned short f2bf(float f) {
    unsigned u = __float_as_uint(f);
    u += 0x7FFF + ((u >> 16) & 1);   // round-to-nearest-even
    return (unsigned short)(u >> 16);
}

// Precompute: b -> bf16 [64][512] (row=r, col=il), a -> bf16 [512][64]
// (row=ok, col=r), w1s = w1 * (1/64). Into d_ws (re-poisoned each call).
__global__ void lokr_pre(const float* __restrict__ w1,
                         const float* __restrict__ a,
                         const float* __restrict__ b,
                         unsigned short* __restrict__ b_bf,
                         unsigned short* __restrict__ a_bf,
                         float* __restrict__ w1s) {
    int i = blockIdx.x * 256 + threadIdx.x;
    if (i < 32768) {
        b_bf[i] = f2bf(b[i]);
        a_bf[i] = f2bf(a[i]);
    }
    if (i < 64) w1s[i] = w1[i] * (1.0f / 64.0f);
}

#define LSTR 72   // LDS row stride in shorts (64 + 8 pad)

__global__ __launch_bounds__(256, 4) void lokr_main(
    const float* __restrict__ x,
    const unsigned short* __restrict__ b_bf,
    const unsigned short* __restrict__ a_bf,
    const float* __restrict__ w1s,
    float* __restrict__ out)
{
    // x tile: 64 rows x 64 k (bf16), double buffered. vs (64 rows x 64 r)
    // aliases xs[0]: last xs[0] read is slab-6 MFMA (pre-barrier), stage 2
    // only starts after that barrier.
    __shared__ __attribute__((aligned(16))) unsigned short xs[2][64 * LSTR];
    __shared__ float w1_s[64];
    unsigned short* vs = &xs[0][0];

    const int t    = threadIdx.x;
    const int wave = t >> 6;
    const int lane = t & 63;
    const int col  = lane & 15;   // MFMA: A row / B col / C col
    const int quad = lane >> 4;
    const long rowbase = (long)blockIdx.x * 64;   // A-row base (8 positions)

    if (t < 64) w1_s[t] = w1s[t];

    // Cooperative-load lane mapping: instr i covers rows lrow+i*16, each
    // 16-lane group reads 256B contiguous of one row.
    const int lrow = t >> 4;          // 0..15
    const int lcol = (t & 15) * 4;    // float col within 64-wide slab

    // ---- preload slab 0 ----
    float4 xb[4];
    {
        const float* xg = x + (rowbase + lrow) * 512 + lcol;
        #pragma unroll
        for (int i = 0; i < 4; ++i)
            xb[i] = *(const float4*)(xg + (long)i * 16 * 512);
    }
    #pragma unroll
    for (int i = 0; i < 4; ++i) {
        s16x4 h;
        h[0] = (short)f2bf(xb[i].x); h[1] = (short)f2bf(xb[i].y);
        h[2] = (short)f2bf(xb[i].z); h[3] = (short)f2bf(xb[i].w);
        *(s16x4*)&xs[0][(lrow + i * 16) * LSTR + lcol] = h;
    }
    __syncthreads();

    // ---- stage 1: T[64 x 64r] accumulated; wave owns r-tile = wave*16 ----
    f32x4 acc[4];
    #pragma unroll
    for (int m = 0; m < 4; ++m) acc[m] = (f32x4){0.f, 0.f, 0.f, 0.f};

    const unsigned short* brow = b_bf + (wave * 16 + col) * 512 + quad * 8;
    s16x8 bc0 = *(const s16x8*)(brow);
    s16x8 bc1 = *(const s16x8*)(brow + 32);

    #pragma unroll 2
    for (int s = 0; s < 8; ++s) {
        s16x8 bn0, bn1;
        // b-frags for next slab first (FIFO: earlier in queue than x loads)
        if (s < 7) {
            bn0 = *(const s16x8*)(brow + (s + 1) * 64);
            bn1 = *(const s16x8*)(brow + (s + 1) * 64 + 32);
            // prefetch x slab s+1 into registers (coalesced)
            const float* xg = x + (rowbase + lrow) * 512 + (s + 1) * 64 + lcol;
            #pragma unroll
            for (int i = 0; i < 4; ++i)
                xb[i] = *(const float4*)(xg + (long)i * 16 * 512);
        }
        // MFMA over 4 m-frags from LDS
        const unsigned short* xa = &xs[s & 1][col * LSTR + quad * 8];
        #pragma unroll
        for (int m = 0; m < 4; ++m) {
            s16x8 a0 = *(const s16x8*)(xa + m * 16 * LSTR);
            s16x8 a1 = *(const s16x8*)(xa + m * 16 * LSTR + 32);
            acc[m] = __builtin_amdgcn_mfma_f32_16x16x32_bf16(a0, bc0, acc[m], 0, 0, 0);
            acc[m] = __builtin_amdgcn_mfma_f32_16x16x32_bf16(a1, bc1, acc[m], 0, 0, 0);
        }
        // stage slab s+1 into the other buffer
        if (s < 7) {
            #pragma unroll
            for (int i = 0; i < 4; ++i) {
                s16x4 h;
                h[0] = (short)f2bf(xb[i].x); h[1] = (short)f2bf(xb[i].y);
                h[2] = (short)f2bf(xb[i].z); h[3] = (short)f2bf(xb[i].w);
                *(s16x4*)&xs[(s + 1) & 1][(lrow + i * 16) * LSTR + lcol] = h;
            }
            __syncthreads();
            bc0 = bn0; bc1 = bn1;
        }
    }

    // ---- stage 2: mix ij->oi with w1, write v (bf16) to LDS (=xs[0]) ----
    // acc[m] C-layout: T row = m*16 + quad*4 + reg, r = wave*16 + col.
    // quads (0,1) hold position 2m, quads (2,3) hold 2m+1; shfl_xor(16)
    // exchanges complementary ij rows; quad&1 splits the 8 oi outputs.
    #pragma unroll
    for (int m = 0; m < 4; ++m) {
        float own[4], oth[4], tij[8];
        #pragma unroll
        for (int j = 0; j < 4; ++j) own[j] = acc[m][j];
        #pragma unroll
        for (int j = 0; j < 4; ++j) oth[j] = __shfl_xor(own[j], 16);
        if ((quad & 1) == 0) {
            #pragma unroll
            for (int j = 0; j < 4; ++j) { tij[j] = own[j]; tij[4 + j] = oth[j]; }
        } else {
            #pragma unroll
            for (int j = 0; j < 4; ++j) { tij[j] = oth[j]; tij[4 + j] = own[j]; }
        }
        const int plocal = m * 2 + (quad >> 1);
        const int oib = (quad & 1) * 4;
        #pragma unroll
        for (int oo = 0; oo < 4; ++oo) {
            float v = 0.f;
            #pragma unroll
            for (int j = 0; j < 8; ++j) v += w1_s[(oib + oo) * 8 + j] * tij[j];
            vs[(plocal * 8 + oib + oo) * LSTR + wave * 16 + col] = f2bf(v);
        }
    }
    __syncthreads();

    // ---- stage 3: out[64 x 512] = v[64 x 64] @ a^T; wave owns 128-wide
    // ok strip. Operands SWAPPED vs stage 1: C[ok][xrow], so lane holds
    // 4 consecutive ok (quad*4+reg) for row m*16+col -> float4 stores.
    s16x8 va0[4], va1[4];
    #pragma unroll
    for (int m = 0; m < 4; ++m) {
        const unsigned short* vp = &vs[(m * 16 + col) * LSTR + quad * 8];
        va0[m] = *(const s16x8*)(vp);
        va1[m] = *(const s16x8*)(vp + 32);
    }

    const unsigned short* ab = a_bf + (wave * 128 + col) * 64 + quad * 8;
    s16x8 ac0 = *(const s16x8*)(ab);
    s16x8 ac1 = *(const s16x8*)(ab + 32);

    // lane's store base: row = rowbase + m*16 + col, col = wave*128 + nt*16 + quad*4
    float* ob = out + (rowbase + col) * 512 + wave * 128 + quad * 4;

    for (int nt = 0; nt < 8; ++nt) {
        s16x8 an0, an1;
        if (nt < 7) {
            an0 = *(const s16x8*)(ab + (nt + 1) * 1024);
            an1 = *(const s16x8*)(ab + (nt + 1) * 1024 + 32);
        }
        #pragma unroll
        for (int m = 0; m < 4; ++m) {
            f32x4 c = {0.f, 0.f, 0.f, 0.f};
            c = __builtin_amdgcn_mfma_f32_16x16x32_bf16(ac0, va0[m], c, 0, 0, 0);
            c = __builtin_amdgcn_mfma_f32_16x16x32_bf16(ac1, va1[m], c, 0, 0, 0);
            *(f32x4*)(ob + (long)m * 16 * 512 + nt * 16) = c;
        }
        if (nt < 7) { ac0 = an0; ac1 = an1; }
    }
}

extern "C" void kernel_launch(void* const* d_in, const int* in_sizes, int n_in,
                              void* d_out, int out_size, void* d_ws, size_t ws_size,
                              hipStream_t stream) {
    const float* x  = (const float*)d_in[0];  // [4,2048,4096]
    const float* w1 = (const float*)d_in[1];  // [8,8]
    const float* a  = (const float*)d_in[2];  // [512,64]
    const float* b  = (const float*)d_in[3];  // [64,512]

    unsigned short* b_bf = (unsigned short*)d_ws;          // 64 KB
    unsigned short* a_bf = b_bf + 32768;                   // 64 KB
    float*          w1s  = (float*)(a_bf + 32768);         // 256 B

    lokr_pre<<<128, 256, 0, stream>>>(w1, a, b, b_bf, a_bf, w1s);
    lokr_main<<<1024, 256, 0, stream>>>(x, b_bf, a_bf, w1s, (float*)d_out);
}